// Round 10
// baseline (614.810 us; speedup 1.0000x reference)
//
#include <hip/hip_runtime.h>

#define N_NODES 100000
#define N_EDGES 1250000
#define IN_CH 128
#define OUT_CH 64

#define NPB 224           // nodes per bin
#define ACCS 65           // acc row stride (pad): 224*65*4 = 58240 B LDS
#define NBINS 447         // ceil(100000/224)
#define BINCAP_DEF 4096   // per-bin edge cap; mean 2796, sigma ~53
#define NB1 256
#define B1T 512
#define CH1 ((N_EDGES + NB1 - 1) / NB1)   // 4883 edges per bin1 block
#define MAXU ((CH1 + B1T - 1) / B1T)      // 10 edges cached per thread
#define CURS_STRIDE 16    // cursor padded to 64 B per bin

typedef __attribute__((ext_vector_type(8))) short short8;
typedef __attribute__((ext_vector_type(4))) float f32x4;

// bin(row) = row / 224 = floor((row>>5)/7), exact for row < 100096
__device__ __host__ inline int bin_of(int row) {
    return (int)((unsigned)((row >> 5) * 9363) >> 16);
}

// round-to-nearest-even f32 -> bf16
__device__ inline unsigned int f2bf(float f) {
    unsigned int u = __float_as_uint(f);
    unsigned int r = ((u >> 16) & 1u) + 0x7FFFu;
    return (u + r) >> 16;
}
__device__ inline float bf_lo(unsigned int p) { return __uint_as_float(p << 16); }
__device__ inline float bf_hi(unsigned int p) { return __uint_as_float(p & 0xFFFF0000u); }

// ---------------------------------------------------------------------------
// Pre-swizzle W[128,64] fp32 -> Wb bf16 in MFMA A-fragment layout.
// Also initializes padded bin cursors.
// ---------------------------------------------------------------------------
__global__ __launch_bounds__(256) void wbconv_kernel(const float* __restrict__ W,
                                                     unsigned int* __restrict__ Wb,
                                                     int* __restrict__ cursor,
                                                     int bincap) {
    int g = blockIdx.x * 256 + threadIdx.x;   // 1024 lane-slots
    if (g < NBINS) cursor[g * CURS_STRIDE] = g * bincap;

    int c = g >> 8;
    int t = (g >> 6) & 3;
    int l = g & 63;
    int q = l >> 4, r15 = l & 15;
    unsigned int o[4];
#pragma unroll
    for (int jj = 0; jj < 4; ++jj) {
        float f0 = W[(c * 32 + q * 8 + 2 * jj)     * OUT_CH + t * 16 + r15];
        float f1 = W[(c * 32 + q * 8 + 2 * jj + 1) * OUT_CH + t * 16 + r15];
        o[jj] = f2bf(f0) | (f2bf(f1) << 16);
    }
    *(uint4*)(Wb + (size_t)g * 4) = make_uint4(o[0], o[1], o[2], o[3]);
}

// ---------------------------------------------------------------------------
// Pass 1: bin edges, single global pass (edges cached in registers).
// One returning global atomic per (block,bin); 8B records.
// Record: x = (rowlocal<<17)|col, y = weight bits.
// ---------------------------------------------------------------------------
__global__ __launch_bounds__(B1T) void bin1_kernel(const int* __restrict__ ei,
                                                   const float* __restrict__ ew,
                                                   int* __restrict__ cursor,
                                                   int2* __restrict__ brec,
                                                   int bincap) {
    __shared__ int hist[NBINS];
    __shared__ int base[NBINS];
    __shared__ int rank[NBINS];
    const int t = threadIdx.x;
    for (int i = t; i < NBINS; i += B1T) { hist[i] = 0; rank[i] = 0; }
    __syncthreads();

    const int e0 = blockIdx.x * CH1;
    const int e1 = (e0 + CH1 < N_EDGES) ? e0 + CH1 : N_EDGES;

    int rowv[MAXU], colv[MAXU];
    float wv[MAXU];
#pragma unroll
    for (int u = 0; u < MAXU; ++u) {
        int e = e0 + t + u * B1T;
        bool ok = e < e1;
        rowv[u] = ok ? ei[e] : -1;
        colv[u] = ok ? ei[N_EDGES + e] : 0;
        wv[u]   = ok ? ew[e] : 0.0f;
        if (ok) atomicAdd(&hist[bin_of(rowv[u])], 1);
    }
    __syncthreads();

    for (int i = t; i < NBINS; i += B1T)
        if (hist[i] > 0) base[i] = atomicAdd(&cursor[i * CURS_STRIDE], hist[i]);
    __syncthreads();

#pragma unroll
    for (int u = 0; u < MAXU; ++u) {
        if (rowv[u] >= 0) {
            int b = bin_of(rowv[u]);
            int rk = atomicAdd(&rank[b], 1);
            int idx = base[b] + rk;
            if (idx < (b + 1) * bincap)       // memory-safety guard only
                brec[idx] = make_int2(((rowv[u] - b * NPB) << 17) | colv[u],
                                      __float_as_int(wv[u]));
        }
    }
}

// ---------------------------------------------------------------------------
// Pass 2 (lite): one block per bin. LDS deg accumulate -> dis. No sort.
// (Direct shared-array fp atomics: proven ds_add_f32 path.)
// ---------------------------------------------------------------------------
__global__ __launch_bounds__(256) void bin2_kernel(const int* __restrict__ cursor,
                                                   const int2* __restrict__ brec,
                                                   float* __restrict__ dis_g,
                                                   int bincap) {
    __shared__ float deg[NPB];
    const int t = threadIdx.x;
    const int b = blockIdx.x;
    if (t < NPB) deg[t] = 0.0f;
    __syncthreads();

    const int rbase = b * bincap;
    int m = cursor[b * CURS_STRIDE] - rbase;
    if (m > bincap) m = bincap;

    for (int j = t; j < m; j += 256) {
        int2 rec = brec[rbase + j];
        atomicAdd(&deg[rec.x >> 17], __int_as_float(rec.y));
    }
    __syncthreads();

    int node = b * NPB + t;
    if (t < NPB && node < N_NODES) {
        float d = deg[t];
        dis_g[node] = (d == 0.0f) ? 0.0f : (1.0f / sqrtf(d));
    }
}

// ---------------------------------------------------------------------------
// GEMM via bf16 MFMA, epilogue pre-scales by dis: hs[i] = (x@W)[i] * dis[i].
// ---------------------------------------------------------------------------
__global__ __launch_bounds__(256) void gemm_kernel(const float* __restrict__ x,
                                                   const unsigned int* __restrict__ Wb,
                                                   const float* __restrict__ dis,
                                                   unsigned int* __restrict__ hs) {
    const int tid  = threadIdx.x;
    const int w    = tid >> 6;
    const int lane = tid & 63;
    const int q    = lane >> 4, r15 = lane & 15;
    const int node = blockIdx.x * 64 + w * 16 + r15;
    const int nl   = (node < N_NODES) ? node : N_NODES - 1;   // clamp loads
    const float* xrow = x + (size_t)nl * IN_CH;

    f32x4 acc[4];
#pragma unroll
    for (int t = 0; t < 4; ++t) acc[t] = (f32x4){0.f, 0.f, 0.f, 0.f};

#pragma unroll
    for (int c = 0; c < 4; ++c) {
        float4 xa = *(const float4*)(xrow + c * 32 + q * 8);
        float4 xb = *(const float4*)(xrow + c * 32 + q * 8 + 4);
        short8 bfrag;
        bfrag[0] = (short)f2bf(xa.x); bfrag[1] = (short)f2bf(xa.y);
        bfrag[2] = (short)f2bf(xa.z); bfrag[3] = (short)f2bf(xa.w);
        bfrag[4] = (short)f2bf(xb.x); bfrag[5] = (short)f2bf(xb.y);
        bfrag[6] = (short)f2bf(xb.z); bfrag[7] = (short)f2bf(xb.w);
#pragma unroll
        for (int t = 0; t < 4; ++t) {
            short8 afrag = *(const short8*)(Wb + (size_t)((c * 4 + t) * 64 + lane) * 4);
            acc[t] = __builtin_amdgcn_mfma_f32_16x16x32_bf16(afrag, bfrag, acc[t], 0, 0, 0);
        }
    }

    if (node < N_NODES) {
        float di = dis[node];
#pragma unroll
        for (int t = 0; t < 4; ++t) {
            unsigned int p0 = f2bf(acc[t][0] * di) | (f2bf(acc[t][1] * di) << 16);
            unsigned int p1 = f2bf(acc[t][2] * di) | (f2bf(acc[t][3] * di) << 16);
            *(uint2*)(hs + (size_t)node * 32 + t * 8 + q * 2) = make_uint2(p0, p1);
        }
    }
}

// ---------------------------------------------------------------------------
// Bin-gather: one block per bin; LDS accumulator acc[NPB][65]. Edge-parallel,
// zero divergence: 8 lanes/edge, lane loads uint4 (8 bf16 ch) of hs[col],
// 8 DIRECT shared-array fp32 atomics (ds_add_f32 — no generic pointers!).
// Epilogue: out = acc * dis + b, coalesced per wave.
// ---------------------------------------------------------------------------
__global__ __launch_bounds__(256) void bingather_kernel(const int* __restrict__ cursor,
                                                        const int2* __restrict__ brec,
                                                        const uint4* __restrict__ hs, // 8/row
                                                        const float* __restrict__ dis,
                                                        const float* __restrict__ b,
                                                        float* __restrict__ out,
                                                        int bincap) {
    __shared__ float acc[NPB * ACCS];
    const int t = threadIdx.x;
    const int blk = blockIdx.x;
    for (int k = t; k < NPB * ACCS; k += 256) acc[k] = 0.0f;
    __syncthreads();

    const int rbase = blk * bincap;
    int m = cursor[blk * CURS_STRIDE] - rbase;
    if (m > bincap) m = bincap;

    const int wid = t >> 6, lane = t & 63;
    const int sub = lane >> 3, l8 = lane & 7;

    for (int j0 = wid * 16; j0 < m; j0 += 64) {
        int jA = j0 + sub;
        int jB = j0 + 8 + sub;
        bool okA = jA < m, okB = jB < m;
        int recA = okA ? brec[rbase + jA].x : 0;
        int recB = okB ? brec[rbase + jB].x : 0;
        uint4 pA = make_uint4(0, 0, 0, 0), pB = make_uint4(0, 0, 0, 0);
        if (okA) pA = hs[(size_t)(recA & 0x1FFFF) * 8 + l8];
        if (okB) pB = hs[(size_t)(recB & 0x1FFFF) * 8 + l8];
        if (okA) {
            int ba = (recA >> 17) * ACCS + 8 * l8;
            atomicAdd(&acc[ba + 0], bf_lo(pA.x)); atomicAdd(&acc[ba + 1], bf_hi(pA.x));
            atomicAdd(&acc[ba + 2], bf_lo(pA.y)); atomicAdd(&acc[ba + 3], bf_hi(pA.y));
            atomicAdd(&acc[ba + 4], bf_lo(pA.z)); atomicAdd(&acc[ba + 5], bf_hi(pA.z));
            atomicAdd(&acc[ba + 6], bf_lo(pA.w)); atomicAdd(&acc[ba + 7], bf_hi(pA.w));
        }
        if (okB) {
            int bb = (recB >> 17) * ACCS + 8 * l8;
            atomicAdd(&acc[bb + 0], bf_lo(pB.x)); atomicAdd(&acc[bb + 1], bf_hi(pB.x));
            atomicAdd(&acc[bb + 2], bf_lo(pB.y)); atomicAdd(&acc[bb + 3], bf_hi(pB.y));
            atomicAdd(&acc[bb + 4], bf_lo(pB.z)); atomicAdd(&acc[bb + 5], bf_hi(pB.z));
            atomicAdd(&acc[bb + 6], bf_lo(pB.w)); atomicAdd(&acc[bb + 7], bf_hi(pB.w));
        }
    }
    __syncthreads();

    // writeout: wave w handles node-locals [w*56, w*56+56); lane = channel
    float bc = b[lane];
#pragma unroll 4
    for (int r = 0; r < 56; ++r) {
        int nl = wid * 56 + r;
        int node = blk * NPB + nl;
        if (node < N_NODES) {
            float di = dis[node];
            out[(size_t)node * OUT_CH + lane] = acc[nl * ACCS + lane] * di + bc;
        }
    }
}

extern "C" void kernel_launch(void* const* d_in, const int* in_sizes, int n_in,
                              void* d_out, int out_size, void* d_ws, size_t ws_size,
                              hipStream_t stream) {
    const float* x  = (const float*)d_in[0];
    const int*   ei = (const int*)d_in[1];
    const float* ew = (const float*)d_in[2];
    const float* W  = (const float*)d_in[3];
    const float* b  = (const float*)d_in[4];
    float* out = (float*)d_out;

    // Workspace layout (4-byte units)
    unsigned int* hs = (unsigned int*)d_ws;                   // N*32 uints (12.8 MB)
    unsigned int* Wb = hs + (size_t)N_NODES * 32;             // 4096 uints
    int*   cursor  = (int*)(Wb + 4096);                       // NBINS*16 (padded)
    float* dis     = (float*)(cursor + NBINS * CURS_STRIDE);  // N
    int2*  brec    = (int2*)(dis + N_NODES);                  // NBINS*bincap int2
    size_t used = (size_t)N_NODES * 32 + 4096 + (size_t)NBINS * CURS_STRIDE
                + (size_t)N_NODES;
    size_t rem  = (ws_size / 4 > used) ? ws_size / 4 - used : 0;
    int bincap  = (int)(rem / (2 * (size_t)NBINS));   // brec = 2 units per slot
    if (bincap > BINCAP_DEF) bincap = BINCAP_DEF;

    wbconv_kernel<<<4, 256, 0, stream>>>(W, Wb, cursor, bincap);
    bin1_kernel<<<NB1, B1T, 0, stream>>>(ei, ew, cursor, brec, bincap);
    bin2_kernel<<<NBINS, 256, 0, stream>>>(cursor, brec, dis, bincap);
    gemm_kernel<<<(N_NODES + 63) / 64, 256, 0, stream>>>(x, Wb, dis, hs);
    bingather_kernel<<<NBINS, 256, 0, stream>>>(cursor, brec, (const uint4*)hs,
                                                dis, b, out, bincap);
}

// Round 11
// 177.735 us; speedup vs baseline: 3.4591x; 3.4591x over previous
//
#include <hip/hip_runtime.h>

#define N_NODES 100000
#define N_EDGES 1250000
#define IN_CH 128
#define OUT_CH 64

#define NPB 128           // nodes per bin; bin = row >> 7
#define ACCS 65           // acc row stride (pad): 128*65*4 = 33280 B LDS
#define NBINS 782         // ceil(100000/128)
#define BINCAP_DEF 2048   // per-bin edge cap; mean 1598, sigma ~40 (+11 sigma)
#define NB1 256
#define B1T 512
#define CH1 ((N_EDGES + NB1 - 1) / NB1)   // 4883 edges per bin1 block
#define MAXU ((CH1 + B1T - 1) / B1T)      // 10 edges cached per thread
#define CURS_STRIDE 16    // cursor padded to 64 B per bin

#define SCALE_ACC 1048576.0f        // 2^20 fixed-point for channel accum
#define INV_SCALE_ACC 9.5367431640625e-07f
#define SCALE_DEG 33554432.0f       // 2^25 fixed-point for degree accum
#define INV_SCALE_DEG 2.9802322387695312e-08f

typedef __attribute__((ext_vector_type(8))) short short8;
typedef __attribute__((ext_vector_type(4))) float f32x4;

// round-to-nearest-even f32 -> bf16
__device__ inline unsigned int f2bf(float f) {
    unsigned int u = __float_as_uint(f);
    unsigned int r = ((u >> 16) & 1u) + 0x7FFFu;
    return (u + r) >> 16;
}
__device__ inline float bf_lo(unsigned int p) { return __uint_as_float(p << 16); }
__device__ inline float bf_hi(unsigned int p) { return __uint_as_float(p & 0xFFFF0000u); }
__device__ inline int q20(float f) { return __float2int_rn(f * SCALE_ACC); }

// ---------------------------------------------------------------------------
// Pre-swizzle W[128,64] fp32 -> Wb bf16 in MFMA A-fragment layout.
// Also initializes padded bin cursors.
// ---------------------------------------------------------------------------
__global__ __launch_bounds__(256) void wbconv_kernel(const float* __restrict__ W,
                                                     unsigned int* __restrict__ Wb,
                                                     int* __restrict__ cursor,
                                                     int bincap) {
    int g = blockIdx.x * 256 + threadIdx.x;   // 1024 lane-slots
    if (g < NBINS) cursor[g * CURS_STRIDE] = g * bincap;

    int c = g >> 8;
    int t = (g >> 6) & 3;
    int l = g & 63;
    int q = l >> 4, r15 = l & 15;
    unsigned int o[4];
#pragma unroll
    for (int jj = 0; jj < 4; ++jj) {
        float f0 = W[(c * 32 + q * 8 + 2 * jj)     * OUT_CH + t * 16 + r15];
        float f1 = W[(c * 32 + q * 8 + 2 * jj + 1) * OUT_CH + t * 16 + r15];
        o[jj] = f2bf(f0) | (f2bf(f1) << 16);
    }
    *(uint4*)(Wb + (size_t)g * 4) = make_uint4(o[0], o[1], o[2], o[3]);
}

// ---------------------------------------------------------------------------
// Pass 1: bin edges by row>>7, single global pass (edges cached in registers).
// One returning global atomic per (block,bin); 8B records.
// Record: x = (rowlocal<<17)|col  (7+17 bits), y = weight bits.
// LDS atomics here are INT (native ds_add) — proven fast.
// ---------------------------------------------------------------------------
__global__ __launch_bounds__(B1T) void bin1_kernel(const int* __restrict__ ei,
                                                   const float* __restrict__ ew,
                                                   int* __restrict__ cursor,
                                                   int2* __restrict__ brec,
                                                   int bincap) {
    __shared__ int hist[NBINS];
    __shared__ int base[NBINS];
    __shared__ int rank[NBINS];
    const int t = threadIdx.x;
    for (int i = t; i < NBINS; i += B1T) { hist[i] = 0; rank[i] = 0; }
    __syncthreads();

    const int e0 = blockIdx.x * CH1;
    const int e1 = (e0 + CH1 < N_EDGES) ? e0 + CH1 : N_EDGES;

    int rowv[MAXU], colv[MAXU];
    float wv[MAXU];
#pragma unroll
    for (int u = 0; u < MAXU; ++u) {
        int e = e0 + t + u * B1T;
        bool ok = e < e1;
        rowv[u] = ok ? ei[e] : -1;
        colv[u] = ok ? ei[N_EDGES + e] : 0;
        wv[u]   = ok ? ew[e] : 0.0f;
        if (ok) atomicAdd(&hist[rowv[u] >> 7], 1);
    }
    __syncthreads();

    for (int i = t; i < NBINS; i += B1T)
        if (hist[i] > 0) base[i] = atomicAdd(&cursor[i * CURS_STRIDE], hist[i]);
    __syncthreads();

#pragma unroll
    for (int u = 0; u < MAXU; ++u) {
        if (rowv[u] >= 0) {
            int b = rowv[u] >> 7;
            int rk = atomicAdd(&rank[b], 1);
            int idx = base[b] + rk;
            if (idx < (b + 1) * bincap)       // memory-safety guard only
                brec[idx] = make_int2(((rowv[u] & 127) << 17) | colv[u],
                                      __float_as_int(wv[u]));
        }
    }
}

// ---------------------------------------------------------------------------
// Pass 2 (lite): one block per bin. INT fixed-point LDS deg accumulate -> dis.
// (fp32 LDS atomicAdd is a CAS loop on this toolchain — int is native.)
// ---------------------------------------------------------------------------
__global__ __launch_bounds__(256) void bin2_kernel(const int* __restrict__ cursor,
                                                   const int2* __restrict__ brec,
                                                   float* __restrict__ dis_g,
                                                   int bincap) {
    __shared__ int deg[NPB];
    const int t = threadIdx.x;
    const int b = blockIdx.x;
    if (t < NPB) deg[t] = 0;
    __syncthreads();

    const int rbase = b * bincap;
    int m = cursor[b * CURS_STRIDE] - rbase;
    if (m > bincap) m = bincap;

    for (int j = t; j < m; j += 256) {
        int2 rec = brec[rbase + j];
        atomicAdd(&deg[rec.x >> 17], __float2int_rn(__int_as_float(rec.y) * SCALE_DEG));
    }
    __syncthreads();

    int node = b * NPB + t;
    if (t < NPB && node < N_NODES) {
        float d = (float)deg[t] * INV_SCALE_DEG;
        dis_g[node] = (d == 0.0f) ? 0.0f : (1.0f / sqrtf(d));
    }
}

// ---------------------------------------------------------------------------
// GEMM via bf16 MFMA, epilogue pre-scales by dis: hs[i] = (x@W)[i] * dis[i].
// ---------------------------------------------------------------------------
__global__ __launch_bounds__(256) void gemm_kernel(const float* __restrict__ x,
                                                   const unsigned int* __restrict__ Wb,
                                                   const float* __restrict__ dis,
                                                   unsigned int* __restrict__ hs) {
    const int tid  = threadIdx.x;
    const int w    = tid >> 6;
    const int lane = tid & 63;
    const int q    = lane >> 4, r15 = lane & 15;
    const int node = blockIdx.x * 64 + w * 16 + r15;
    const int nl   = (node < N_NODES) ? node : N_NODES - 1;   // clamp loads
    const float* xrow = x + (size_t)nl * IN_CH;

    f32x4 acc[4];
#pragma unroll
    for (int t = 0; t < 4; ++t) acc[t] = (f32x4){0.f, 0.f, 0.f, 0.f};

#pragma unroll
    for (int c = 0; c < 4; ++c) {
        float4 xa = *(const float4*)(xrow + c * 32 + q * 8);
        float4 xb = *(const float4*)(xrow + c * 32 + q * 8 + 4);
        short8 bfrag;
        bfrag[0] = (short)f2bf(xa.x); bfrag[1] = (short)f2bf(xa.y);
        bfrag[2] = (short)f2bf(xa.z); bfrag[3] = (short)f2bf(xa.w);
        bfrag[4] = (short)f2bf(xb.x); bfrag[5] = (short)f2bf(xb.y);
        bfrag[6] = (short)f2bf(xb.z); bfrag[7] = (short)f2bf(xb.w);
#pragma unroll
        for (int t = 0; t < 4; ++t) {
            short8 afrag = *(const short8*)(Wb + (size_t)((c * 4 + t) * 64 + lane) * 4);
            acc[t] = __builtin_amdgcn_mfma_f32_16x16x32_bf16(afrag, bfrag, acc[t], 0, 0, 0);
        }
    }

    if (node < N_NODES) {
        float di = dis[node];
#pragma unroll
        for (int t = 0; t < 4; ++t) {
            unsigned int p0 = f2bf(acc[t][0] * di) | (f2bf(acc[t][1] * di) << 16);
            unsigned int p1 = f2bf(acc[t][2] * di) | (f2bf(acc[t][3] * di) << 16);
            *(uint2*)(hs + (size_t)node * 32 + t * 8 + q * 2) = make_uint2(p0, p1);
        }
    }
}

// ---------------------------------------------------------------------------
// Bin-gather: one block per 128-node bin; LDS int accumulator acc[128][65]
// (33 KB -> 4 blocks/CU). Edge-parallel, zero divergence: 8 lanes/edge, lane
// loads uint4 (8 bf16 ch) of hs[col], does 8 native ds_add_u32 fixed-point
// atomics (2^20 scale). Epilogue: out = acc * 2^-20 * dis + b, coalesced.
// ---------------------------------------------------------------------------
__global__ __launch_bounds__(256) void bingather_kernel(const int* __restrict__ cursor,
                                                        const int2* __restrict__ brec,
                                                        const uint4* __restrict__ hs, // 8/row
                                                        const float* __restrict__ dis,
                                                        const float* __restrict__ b,
                                                        float* __restrict__ out,
                                                        int bincap) {
    __shared__ int acc[NPB * ACCS];
    const int t = threadIdx.x;
    const int blk = blockIdx.x;
    for (int k = t; k < NPB * ACCS; k += 256) acc[k] = 0;
    __syncthreads();

    const int rbase = blk * bincap;
    int m = cursor[blk * CURS_STRIDE] - rbase;
    if (m > bincap) m = bincap;

    const int wid = t >> 6, lane = t & 63;
    const int sub = lane >> 3, l8 = lane & 7;

    for (int j0 = wid * 16; j0 < m; j0 += 64) {
        int jA = j0 + sub;
        int jB = j0 + 8 + sub;
        bool okA = jA < m, okB = jB < m;
        int recA = okA ? brec[rbase + jA].x : 0;
        int recB = okB ? brec[rbase + jB].x : 0;
        uint4 pA = make_uint4(0, 0, 0, 0), pB = make_uint4(0, 0, 0, 0);
        if (okA) pA = hs[(size_t)(recA & 0x1FFFF) * 8 + l8];
        if (okB) pB = hs[(size_t)(recB & 0x1FFFF) * 8 + l8];
        if (okA) {
            int ba = (recA >> 17) * ACCS + 8 * l8;
            atomicAdd(&acc[ba + 0], q20(bf_lo(pA.x))); atomicAdd(&acc[ba + 1], q20(bf_hi(pA.x)));
            atomicAdd(&acc[ba + 2], q20(bf_lo(pA.y))); atomicAdd(&acc[ba + 3], q20(bf_hi(pA.y)));
            atomicAdd(&acc[ba + 4], q20(bf_lo(pA.z))); atomicAdd(&acc[ba + 5], q20(bf_hi(pA.z)));
            atomicAdd(&acc[ba + 6], q20(bf_lo(pA.w))); atomicAdd(&acc[ba + 7], q20(bf_hi(pA.w)));
        }
        if (okB) {
            int bb = (recB >> 17) * ACCS + 8 * l8;
            atomicAdd(&acc[bb + 0], q20(bf_lo(pB.x))); atomicAdd(&acc[bb + 1], q20(bf_hi(pB.x)));
            atomicAdd(&acc[bb + 2], q20(bf_lo(pB.y))); atomicAdd(&acc[bb + 3], q20(bf_hi(pB.y)));
            atomicAdd(&acc[bb + 4], q20(bf_lo(pB.z))); atomicAdd(&acc[bb + 5], q20(bf_hi(pB.z)));
            atomicAdd(&acc[bb + 6], q20(bf_lo(pB.w))); atomicAdd(&acc[bb + 7], q20(bf_hi(pB.w)));
        }
    }
    __syncthreads();

    // writeout: wave w handles node-locals [w*32, w*32+32); lane = channel
    float bc = b[lane];
#pragma unroll 4
    for (int r = 0; r < 32; ++r) {
        int nl = wid * 32 + r;
        int node = blk * NPB + nl;
        if (node < N_NODES) {
            float di = dis[node] * INV_SCALE_ACC;
            out[(size_t)node * OUT_CH + lane] = (float)acc[nl * ACCS + lane] * di + bc;
        }
    }
}

extern "C" void kernel_launch(void* const* d_in, const int* in_sizes, int n_in,
                              void* d_out, int out_size, void* d_ws, size_t ws_size,
                              hipStream_t stream) {
    const float* x  = (const float*)d_in[0];
    const int*   ei = (const int*)d_in[1];
    const float* ew = (const float*)d_in[2];
    const float* W  = (const float*)d_in[3];
    const float* b  = (const float*)d_in[4];
    float* out = (float*)d_out;

    // Workspace layout (4-byte units)
    unsigned int* hs = (unsigned int*)d_ws;                   // N*32 uints (12.8 MB)
    unsigned int* Wb = hs + (size_t)N_NODES * 32;             // 4096 uints
    int*   cursor  = (int*)(Wb + 4096);                       // NBINS*16 (padded)
    float* dis     = (float*)(cursor + NBINS * CURS_STRIDE);  // N
    int2*  brec    = (int2*)(dis + N_NODES);                  // NBINS*bincap int2
    size_t used = (size_t)N_NODES * 32 + 4096 + (size_t)NBINS * CURS_STRIDE
                + (size_t)N_NODES;
    size_t rem  = (ws_size / 4 > used) ? ws_size / 4 - used : 0;
    int bincap  = (int)(rem / (2 * (size_t)NBINS));   // brec = 2 units per slot
    if (bincap > BINCAP_DEF) bincap = BINCAP_DEF;

    wbconv_kernel<<<4, 256, 0, stream>>>(W, Wb, cursor, bincap);
    bin1_kernel<<<NB1, B1T, 0, stream>>>(ei, ew, cursor, brec, bincap);
    bin2_kernel<<<NBINS, 256, 0, stream>>>(cursor, brec, dis, bincap);
    gemm_kernel<<<(N_NODES + 63) / 64, 256, 0, stream>>>(x, Wb, dis, hs);
    bingather_kernel<<<NBINS, 256, 0, stream>>>(cursor, brec, (const uint4*)hs,
                                                dis, b, out, bincap);
}

// Round 12
// 167.260 us; speedup vs baseline: 3.6758x; 1.0626x over previous
//
#include <hip/hip_runtime.h>

#define N_NODES 100000
#define N_EDGES 1250000
#define IN_CH 128
#define OUT_CH 64

#define NPB 128           // nodes per bin; bin = row >> 7
#define ACCS 65           // acc row stride (pad): 128*65*4 = 33280 B LDS
#define NBINS 782         // ceil(100000/128)
#define BINCAP_DEF 2048   // per-bin edge cap; mean 1598, sigma ~40 (+11 sigma)
#define NB1 256
#define B1T 512
#define CH1 ((N_EDGES + NB1 - 1) / NB1)   // 4883 edges per bin1 block
#define MAXU ((CH1 + B1T - 1) / B1T)      // 10 edges cached per thread
#define CURS_STRIDE 16    // cursor padded to 64 B per bin

#define EXP20 0x0A000000u           // +20 in the fp32 exponent field (x -> x*2^20)
#define INV_SCALE_ACC 9.5367431640625e-07f   // 2^-20
#define SCALE_DEG 33554432.0f       // 2^25 fixed-point for degree accum
#define INV_SCALE_DEG 2.9802322387695312e-08f

typedef __attribute__((ext_vector_type(8))) short short8;
typedef __attribute__((ext_vector_type(4))) float f32x4;

// round-to-nearest-even f32 -> bf16
__device__ inline unsigned int f2bf(float f) {
    unsigned int u = __float_as_uint(f);
    unsigned int r = ((u >> 16) & 1u) + 0x7FFFu;
    return (u + r) >> 16;
}
__device__ inline float bf_lo(unsigned int p) { return __uint_as_float(p << 16); }
__device__ inline float bf_hi(unsigned int p) { return __uint_as_float(p & 0xFFFF0000u); }

// q20 of packed bf16 halves via exponent-add: int(float(bf)*2^20), trunc.
// (adding 20<<23 touches only bits >=23; zero/denorm collapse to 0 on cvt)
__device__ inline int qlo(unsigned int p, unsigned int k) {
    return (int)__uint_as_float((p << 16) + k);
}
__device__ inline int qhi(unsigned int p, unsigned int k) {
    return (int)__uint_as_float((p & 0xFFFF0000u) + k);
}

// ---------------------------------------------------------------------------
// Pre-swizzle W[128,64] fp32 -> Wb bf16 in MFMA A-fragment layout.
// Also initializes padded bin cursors.
// ---------------------------------------------------------------------------
__global__ __launch_bounds__(256) void wbconv_kernel(const float* __restrict__ W,
                                                     unsigned int* __restrict__ Wb,
                                                     int* __restrict__ cursor,
                                                     int bincap) {
    int g = blockIdx.x * 256 + threadIdx.x;   // 1024 lane-slots
    if (g < NBINS) cursor[g * CURS_STRIDE] = g * bincap;

    int c = g >> 8;
    int t = (g >> 6) & 3;
    int l = g & 63;
    int q = l >> 4, r15 = l & 15;
    unsigned int o[4];
#pragma unroll
    for (int jj = 0; jj < 4; ++jj) {
        float f0 = W[(c * 32 + q * 8 + 2 * jj)     * OUT_CH + t * 16 + r15];
        float f1 = W[(c * 32 + q * 8 + 2 * jj + 1) * OUT_CH + t * 16 + r15];
        o[jj] = f2bf(f0) | (f2bf(f1) << 16);
    }
    *(uint4*)(Wb + (size_t)g * 4) = make_uint4(o[0], o[1], o[2], o[3]);
}

// ---------------------------------------------------------------------------
// Pass 1: bin edges by row>>7, single global pass (edges cached in registers).
// One returning global atomic per (block,bin); 8B records.
// Record: x = (rowlocal<<17)|col  (7+17 bits), y = weight bits.
// ---------------------------------------------------------------------------
__global__ __launch_bounds__(B1T) void bin1_kernel(const int* __restrict__ ei,
                                                   const float* __restrict__ ew,
                                                   int* __restrict__ cursor,
                                                   int2* __restrict__ brec,
                                                   int bincap) {
    __shared__ int hist[NBINS];
    __shared__ int base[NBINS];
    __shared__ int rank[NBINS];
    const int t = threadIdx.x;
    for (int i = t; i < NBINS; i += B1T) { hist[i] = 0; rank[i] = 0; }
    __syncthreads();

    const int e0 = blockIdx.x * CH1;
    const int e1 = (e0 + CH1 < N_EDGES) ? e0 + CH1 : N_EDGES;

    int rowv[MAXU], colv[MAXU];
    float wv[MAXU];
#pragma unroll
    for (int u = 0; u < MAXU; ++u) {
        int e = e0 + t + u * B1T;
        bool ok = e < e1;
        rowv[u] = ok ? ei[e] : -1;
        colv[u] = ok ? ei[N_EDGES + e] : 0;
        wv[u]   = ok ? ew[e] : 0.0f;
        if (ok) atomicAdd(&hist[rowv[u] >> 7], 1);
    }
    __syncthreads();

    for (int i = t; i < NBINS; i += B1T)
        if (hist[i] > 0) base[i] = atomicAdd(&cursor[i * CURS_STRIDE], hist[i]);
    __syncthreads();

#pragma unroll
    for (int u = 0; u < MAXU; ++u) {
        if (rowv[u] >= 0) {
            int b = rowv[u] >> 7;
            int rk = atomicAdd(&rank[b], 1);
            int idx = base[b] + rk;
            if (idx < (b + 1) * bincap)       // memory-safety guard only
                brec[idx] = make_int2(((rowv[u] & 127) << 17) | colv[u],
                                      __float_as_int(wv[u]));
        }
    }
}

// ---------------------------------------------------------------------------
// Pass 2 (lite): one block per bin. INT fixed-point LDS deg accumulate -> dis.
// ---------------------------------------------------------------------------
__global__ __launch_bounds__(256) void bin2_kernel(const int* __restrict__ cursor,
                                                   const int2* __restrict__ brec,
                                                   float* __restrict__ dis_g,
                                                   int bincap) {
    __shared__ int deg[NPB];
    const int t = threadIdx.x;
    const int b = blockIdx.x;
    if (t < NPB) deg[t] = 0;
    __syncthreads();

    const int rbase = b * bincap;
    int m = cursor[b * CURS_STRIDE] - rbase;
    if (m > bincap) m = bincap;

    for (int j = t; j < m; j += 256) {
        int2 rec = brec[rbase + j];
        atomicAdd(&deg[rec.x >> 17], __float2int_rn(__int_as_float(rec.y) * SCALE_DEG));
    }
    __syncthreads();

    int node = b * NPB + t;
    if (t < NPB && node < N_NODES) {
        float d = (float)deg[t] * INV_SCALE_DEG;
        dis_g[node] = (d == 0.0f) ? 0.0f : (1.0f / sqrtf(d));
    }
}

// ---------------------------------------------------------------------------
// GEMM via bf16 MFMA, epilogue pre-scales by dis: hs[i] = (x@W)[i] * dis[i].
// ---------------------------------------------------------------------------
__global__ __launch_bounds__(256) void gemm_kernel(const float* __restrict__ x,
                                                   const unsigned int* __restrict__ Wb,
                                                   const float* __restrict__ dis,
                                                   unsigned int* __restrict__ hs) {
    const int tid  = threadIdx.x;
    const int w    = tid >> 6;
    const int lane = tid & 63;
    const int q    = lane >> 4, r15 = lane & 15;
    const int node = blockIdx.x * 64 + w * 16 + r15;
    const int nl   = (node < N_NODES) ? node : N_NODES - 1;   // clamp loads
    const float* xrow = x + (size_t)nl * IN_CH;

    f32x4 acc[4];
#pragma unroll
    for (int t = 0; t < 4; ++t) acc[t] = (f32x4){0.f, 0.f, 0.f, 0.f};

#pragma unroll
    for (int c = 0; c < 4; ++c) {
        float4 xa = *(const float4*)(xrow + c * 32 + q * 8);
        float4 xb = *(const float4*)(xrow + c * 32 + q * 8 + 4);
        short8 bfrag;
        bfrag[0] = (short)f2bf(xa.x); bfrag[1] = (short)f2bf(xa.y);
        bfrag[2] = (short)f2bf(xa.z); bfrag[3] = (short)f2bf(xa.w);
        bfrag[4] = (short)f2bf(xb.x); bfrag[5] = (short)f2bf(xb.y);
        bfrag[6] = (short)f2bf(xb.z); bfrag[7] = (short)f2bf(xb.w);
#pragma unroll
        for (int t = 0; t < 4; ++t) {
            short8 afrag = *(const short8*)(Wb + (size_t)((c * 4 + t) * 64 + lane) * 4);
            acc[t] = __builtin_amdgcn_mfma_f32_16x16x32_bf16(afrag, bfrag, acc[t], 0, 0, 0);
        }
    }

    if (node < N_NODES) {
        float di = dis[node];
#pragma unroll
        for (int t = 0; t < 4; ++t) {
            unsigned int p0 = f2bf(acc[t][0] * di) | (f2bf(acc[t][1] * di) << 16);
            unsigned int p1 = f2bf(acc[t][2] * di) | (f2bf(acc[t][3] * di) << 16);
            *(uint2*)(hs + (size_t)node * 32 + t * 8 + q * 2) = make_uint2(p0, p1);
        }
    }
}

// ---------------------------------------------------------------------------
// Bin-gather: one 512-thread block per 128-node bin; LDS int accumulator
// acc[128][65] (33 KB -> 4 blocks/CU = 32 waves/CU). 8 lanes/edge, lane loads
// uint4 (8 bf16 ch) of hs[col], does 8 native ds_add_u32 with the quantize
// folded into one exponent-add (qlo/qhi). out = acc * 2^-20 * dis + b.
// ---------------------------------------------------------------------------
__global__ __launch_bounds__(512) void bingather_kernel(const int* __restrict__ cursor,
                                                        const int2* __restrict__ brec,
                                                        const uint4* __restrict__ hs, // 8/row
                                                        const float* __restrict__ dis,
                                                        const float* __restrict__ b,
                                                        float* __restrict__ out,
                                                        int bincap) {
    __shared__ int acc[NPB * ACCS];
    const int t = threadIdx.x;
    const int blk = blockIdx.x;
    for (int k = t; k < NPB * ACCS; k += 512) acc[k] = 0;
    __syncthreads();

    const int rbase = blk * bincap;
    int m = cursor[blk * CURS_STRIDE] - rbase;
    if (m > bincap) m = bincap;

    const int wid = t >> 6, lane = t & 63;
    const int sub = lane >> 3, l8 = lane & 7;
    const unsigned int K = EXP20;   // kept in SGPR

    for (int j0 = wid * 16; j0 < m; j0 += 128) {
        int jA = j0 + sub;
        int jB = j0 + 8 + sub;
        bool okA = jA < m, okB = jB < m;
        int recA = okA ? brec[rbase + jA].x : 0;
        int recB = okB ? brec[rbase + jB].x : 0;
        uint4 pA = make_uint4(0, 0, 0, 0), pB = make_uint4(0, 0, 0, 0);
        if (okA) pA = hs[(size_t)(recA & 0x1FFFF) * 8 + l8];
        if (okB) pB = hs[(size_t)(recB & 0x1FFFF) * 8 + l8];
        if (okA) {
            int ba = (recA >> 17) * ACCS + 8 * l8;
            atomicAdd(&acc[ba + 0], qlo(pA.x, K)); atomicAdd(&acc[ba + 1], qhi(pA.x, K));
            atomicAdd(&acc[ba + 2], qlo(pA.y, K)); atomicAdd(&acc[ba + 3], qhi(pA.y, K));
            atomicAdd(&acc[ba + 4], qlo(pA.z, K)); atomicAdd(&acc[ba + 5], qhi(pA.z, K));
            atomicAdd(&acc[ba + 6], qlo(pA.w, K)); atomicAdd(&acc[ba + 7], qhi(pA.w, K));
        }
        if (okB) {
            int bb = (recB >> 17) * ACCS + 8 * l8;
            atomicAdd(&acc[bb + 0], qlo(pB.x, K)); atomicAdd(&acc[bb + 1], qhi(pB.x, K));
            atomicAdd(&acc[bb + 2], qlo(pB.y, K)); atomicAdd(&acc[bb + 3], qhi(pB.y, K));
            atomicAdd(&acc[bb + 4], qlo(pB.z, K)); atomicAdd(&acc[bb + 5], qhi(pB.z, K));
            atomicAdd(&acc[bb + 6], qlo(pB.w, K)); atomicAdd(&acc[bb + 7], qhi(pB.w, K));
        }
    }
    __syncthreads();

    // writeout: wave w handles node-locals [w*16, w*16+16); lane = channel
    float bc = b[lane];
#pragma unroll 4
    for (int r = 0; r < 16; ++r) {
        int nl = wid * 16 + r;
        int node = blk * NPB + nl;
        if (node < N_NODES) {
            float di = dis[node] * INV_SCALE_ACC;
            out[(size_t)node * OUT_CH + lane] = (float)acc[nl * ACCS + lane] * di + bc;
        }
    }
}

extern "C" void kernel_launch(void* const* d_in, const int* in_sizes, int n_in,
                              void* d_out, int out_size, void* d_ws, size_t ws_size,
                              hipStream_t stream) {
    const float* x  = (const float*)d_in[0];
    const int*   ei = (const int*)d_in[1];
    const float* ew = (const float*)d_in[2];
    const float* W  = (const float*)d_in[3];
    const float* b  = (const float*)d_in[4];
    float* out = (float*)d_out;

    // Workspace layout (4-byte units)
    unsigned int* hs = (unsigned int*)d_ws;                   // N*32 uints (12.8 MB)
    unsigned int* Wb = hs + (size_t)N_NODES * 32;             // 4096 uints
    int*   cursor  = (int*)(Wb + 4096);                       // NBINS*16 (padded)
    float* dis     = (float*)(cursor + NBINS * CURS_STRIDE);  // N
    int2*  brec    = (int2*)(dis + N_NODES);                  // NBINS*bincap int2
    size_t used = (size_t)N_NODES * 32 + 4096 + (size_t)NBINS * CURS_STRIDE
                + (size_t)N_NODES;
    size_t rem  = (ws_size / 4 > used) ? ws_size / 4 - used : 0;
    int bincap  = (int)(rem / (2 * (size_t)NBINS));   // brec = 2 units per slot
    if (bincap > BINCAP_DEF) bincap = BINCAP_DEF;

    wbconv_kernel<<<4, 256, 0, stream>>>(W, Wb, cursor, bincap);
    bin1_kernel<<<NB1, B1T, 0, stream>>>(ei, ew, cursor, brec, bincap);
    bin2_kernel<<<NBINS, 256, 0, stream>>>(cursor, brec, dis, bincap);
    gemm_kernel<<<(N_NODES + 63) / 64, 256, 0, stream>>>(x, Wb, dis, hs);
    bingather_kernel<<<NBINS, 512, 0, stream>>>(cursor, brec, (const uint4*)hs,
                                                dis, b, out, bincap);
}

// Round 13
// 163.984 us; speedup vs baseline: 3.7492x; 1.0200x over previous
//
#include <hip/hip_runtime.h>

#define N_NODES 100000
#define N_EDGES 1250000
#define IN_CH 128
#define OUT_CH 64

#define NPB 128           // nodes per bin; bin = row >> 7
#define ACCS2 33          // u64 acc row stride (pad): 128*33*8 = 33792 B LDS
#define NBINS 782         // ceil(100000/128)
#define BINCAP_DEF 2048   // per-bin edge cap; mean 1598, sigma ~40 (+11 sigma)
#define NB1 256
#define B1T 512
#define CH1 ((N_EDGES + NB1 - 1) / NB1)   // 4883 edges per bin1 block
#define MAXU ((CH1 + B1T - 1) / B1T)      // 10 edges cached per thread
#define CURS_STRIDE 16    // cursor padded to 64 B per bin

// fixed-point: q = rn(val * 2^13), biased by 2^24 per contribution (sign-safe)
#define QSCALE 8192.0f
#define QBIAS_F 16777216.0f
#define QBIAS_U 16777216u
#define INV_QSCALE 1.220703125e-4f   // 2^-13
#define SCALE_DEG 33554432.0f        // 2^25 fixed-point for degree accum
#define INV_SCALE_DEG 2.9802322387695312e-08f

typedef __attribute__((ext_vector_type(8))) short short8;
typedef __attribute__((ext_vector_type(4))) float f32x4;

// round-to-nearest-even f32 -> bf16
__device__ inline unsigned int f2bf(float f) {
    unsigned int u = __float_as_uint(f);
    unsigned int r = ((u >> 16) & 1u) + 0x7FFFu;
    return (u + r) >> 16;
}
__device__ inline float bf_lo(unsigned int p) { return __uint_as_float(p << 16); }
__device__ inline float bf_hi(unsigned int p) { return __uint_as_float(p & 0xFFFF0000u); }

// biased fixed-point quantize of one packed bf16x2 -> u64 {lo: ch0, hi: ch1}
__device__ inline unsigned long long qpack(unsigned int p) {
    unsigned int lo = (unsigned int)__float2int_rn(fmaf(bf_lo(p), QSCALE, QBIAS_F));
    unsigned int hi = (unsigned int)__float2int_rn(fmaf(bf_hi(p), QSCALE, QBIAS_F));
    return ((unsigned long long)hi << 32) | (unsigned long long)lo;
}

// ---------------------------------------------------------------------------
// Pre-swizzle W[128,64] fp32 -> Wb bf16 in MFMA A-fragment layout.
// Also initializes padded bin cursors.
// ---------------------------------------------------------------------------
__global__ __launch_bounds__(256) void wbconv_kernel(const float* __restrict__ W,
                                                     unsigned int* __restrict__ Wb,
                                                     int* __restrict__ cursor,
                                                     int bincap) {
    int g = blockIdx.x * 256 + threadIdx.x;   // 1024 lane-slots
    if (g < NBINS) cursor[g * CURS_STRIDE] = g * bincap;

    int c = g >> 8;
    int t = (g >> 6) & 3;
    int l = g & 63;
    int q = l >> 4, r15 = l & 15;
    unsigned int o[4];
#pragma unroll
    for (int jj = 0; jj < 4; ++jj) {
        float f0 = W[(c * 32 + q * 8 + 2 * jj)     * OUT_CH + t * 16 + r15];
        float f1 = W[(c * 32 + q * 8 + 2 * jj + 1) * OUT_CH + t * 16 + r15];
        o[jj] = f2bf(f0) | (f2bf(f1) << 16);
    }
    *(uint4*)(Wb + (size_t)g * 4) = make_uint4(o[0], o[1], o[2], o[3]);
}

// ---------------------------------------------------------------------------
// Pass 1: bin edges by row>>7, single global pass (edges cached in registers).
// One returning global atomic per (block,bin); 8B records.
// Record: x = (rowlocal<<17)|col  (7+17 bits), y = weight bits.
// ---------------------------------------------------------------------------
__global__ __launch_bounds__(B1T) void bin1_kernel(const int* __restrict__ ei,
                                                   const float* __restrict__ ew,
                                                   int* __restrict__ cursor,
                                                   int2* __restrict__ brec,
                                                   int bincap) {
    __shared__ int hist[NBINS];
    __shared__ int base[NBINS];
    __shared__ int rank[NBINS];
    const int t = threadIdx.x;
    for (int i = t; i < NBINS; i += B1T) { hist[i] = 0; rank[i] = 0; }
    __syncthreads();

    const int e0 = blockIdx.x * CH1;
    const int e1 = (e0 + CH1 < N_EDGES) ? e0 + CH1 : N_EDGES;

    int rowv[MAXU], colv[MAXU];
    float wv[MAXU];
#pragma unroll
    for (int u = 0; u < MAXU; ++u) {
        int e = e0 + t + u * B1T;
        bool ok = e < e1;
        rowv[u] = ok ? ei[e] : -1;
        colv[u] = ok ? ei[N_EDGES + e] : 0;
        wv[u]   = ok ? ew[e] : 0.0f;
        if (ok) atomicAdd(&hist[rowv[u] >> 7], 1);
    }
    __syncthreads();

    for (int i = t; i < NBINS; i += B1T)
        if (hist[i] > 0) base[i] = atomicAdd(&cursor[i * CURS_STRIDE], hist[i]);
    __syncthreads();

#pragma unroll
    for (int u = 0; u < MAXU; ++u) {
        if (rowv[u] >= 0) {
            int b = rowv[u] >> 7;
            int rk = atomicAdd(&rank[b], 1);
            int idx = base[b] + rk;
            if (idx < (b + 1) * bincap)       // memory-safety guard only
                brec[idx] = make_int2(((rowv[u] & 127) << 17) | colv[u],
                                      __float_as_int(wv[u]));
        }
    }
}

// ---------------------------------------------------------------------------
// Pass 2 (lite): one block per bin. INT fixed-point LDS deg accumulate -> dis.
// ---------------------------------------------------------------------------
__global__ __launch_bounds__(256) void bin2_kernel(const int* __restrict__ cursor,
                                                   const int2* __restrict__ brec,
                                                   float* __restrict__ dis_g,
                                                   int bincap) {
    __shared__ int deg[NPB];
    const int t = threadIdx.x;
    const int b = blockIdx.x;
    if (t < NPB) deg[t] = 0;
    __syncthreads();

    const int rbase = b * bincap;
    int m = cursor[b * CURS_STRIDE] - rbase;
    if (m > bincap) m = bincap;

    for (int j = t; j < m; j += 256) {
        int2 rec = brec[rbase + j];
        atomicAdd(&deg[rec.x >> 17], __float2int_rn(__int_as_float(rec.y) * SCALE_DEG));
    }
    __syncthreads();

    int node = b * NPB + t;
    if (t < NPB && node < N_NODES) {
        float d = (float)deg[t] * INV_SCALE_DEG;
        dis_g[node] = (d == 0.0f) ? 0.0f : (1.0f / sqrtf(d));
    }
}

// ---------------------------------------------------------------------------
// GEMM via bf16 MFMA, epilogue pre-scales by dis: hs[i] = (x@W)[i] * dis[i].
// ---------------------------------------------------------------------------
__global__ __launch_bounds__(256) void gemm_kernel(const float* __restrict__ x,
                                                   const unsigned int* __restrict__ Wb,
                                                   const float* __restrict__ dis,
                                                   unsigned int* __restrict__ hs) {
    const int tid  = threadIdx.x;
    const int w    = tid >> 6;
    const int lane = tid & 63;
    const int q    = lane >> 4, r15 = lane & 15;
    const int node = blockIdx.x * 64 + w * 16 + r15;
    const int nl   = (node < N_NODES) ? node : N_NODES - 1;   // clamp loads
    const float* xrow = x + (size_t)nl * IN_CH;

    f32x4 acc[4];
#pragma unroll
    for (int t = 0; t < 4; ++t) acc[t] = (f32x4){0.f, 0.f, 0.f, 0.f};

#pragma unroll
    for (int c = 0; c < 4; ++c) {
        float4 xa = *(const float4*)(xrow + c * 32 + q * 8);
        float4 xb = *(const float4*)(xrow + c * 32 + q * 8 + 4);
        short8 bfrag;
        bfrag[0] = (short)f2bf(xa.x); bfrag[1] = (short)f2bf(xa.y);
        bfrag[2] = (short)f2bf(xa.z); bfrag[3] = (short)f2bf(xa.w);
        bfrag[4] = (short)f2bf(xb.x); bfrag[5] = (short)f2bf(xb.y);
        bfrag[6] = (short)f2bf(xb.z); bfrag[7] = (short)f2bf(xb.w);
#pragma unroll
        for (int t = 0; t < 4; ++t) {
            short8 afrag = *(const short8*)(Wb + (size_t)((c * 4 + t) * 64 + lane) * 4);
            acc[t] = __builtin_amdgcn_mfma_f32_16x16x32_bf16(afrag, bfrag, acc[t], 0, 0, 0);
        }
    }

    if (node < N_NODES) {
        float di = dis[node];
#pragma unroll
        for (int t = 0; t < 4; ++t) {
            unsigned int p0 = f2bf(acc[t][0] * di) | (f2bf(acc[t][1] * di) << 16);
            unsigned int p1 = f2bf(acc[t][2] * di) | (f2bf(acc[t][3] * di) << 16);
            *(uint2*)(hs + (size_t)node * 32 + t * 8 + q * 2) = make_uint2(p0, p1);
        }
    }
}

// ---------------------------------------------------------------------------
// Bin-gather: one 512-thread block per 128-node bin. u64-packed LDS atomics:
// each ds_add_u64 accumulates TWO biased fixed-point channels (lo/hi 32-bit,
// bias 2^24/contribution guarantees non-negative halves -> no cross-carry;
// lo-half total < 2^31). Per-row edge count in cnt[] for bias removal.
// Per 8-edge group: 4 ds_add_u64 + 1 cnt add (vs 8 ds_add_u32 before).
// ---------------------------------------------------------------------------
__global__ __launch_bounds__(512) void bingather_kernel(const int* __restrict__ cursor,
                                                        const int2* __restrict__ brec,
                                                        const uint4* __restrict__ hs, // 8/row
                                                        const float* __restrict__ dis,
                                                        const float* __restrict__ b,
                                                        float* __restrict__ out,
                                                        int bincap) {
    __shared__ unsigned long long acc[NPB * ACCS2];   // 33792 B
    __shared__ int cnt[NPB];
    const int t = threadIdx.x;
    const int blk = blockIdx.x;
    for (int k = t; k < NPB * ACCS2; k += 512) acc[k] = 0ull;
    if (t < NPB) cnt[t] = 0;
    __syncthreads();

    const int rbase = blk * bincap;
    int m = cursor[blk * CURS_STRIDE] - rbase;
    if (m > bincap) m = bincap;

    const int wid = t >> 6, lane = t & 63;
    const int sub = lane >> 3, l8 = lane & 7;

    for (int j0 = wid * 16; j0 < m; j0 += 128) {
        int jA = j0 + sub;
        int jB = j0 + 8 + sub;
        bool okA = jA < m, okB = jB < m;
        int recA = okA ? brec[rbase + jA].x : 0;
        int recB = okB ? brec[rbase + jB].x : 0;
        uint4 pA = make_uint4(0, 0, 0, 0), pB = make_uint4(0, 0, 0, 0);
        if (okA) pA = hs[(size_t)(recA & 0x1FFFF) * 8 + l8];
        if (okB) pB = hs[(size_t)(recB & 0x1FFFF) * 8 + l8];
        if (okA) {
            int ba = (recA >> 17) * ACCS2 + 4 * l8;
            atomicAdd(&acc[ba + 0], qpack(pA.x));
            atomicAdd(&acc[ba + 1], qpack(pA.y));
            atomicAdd(&acc[ba + 2], qpack(pA.z));
            atomicAdd(&acc[ba + 3], qpack(pA.w));
            if (l8 == 0) atomicAdd(&cnt[recA >> 17], 1);
        }
        if (okB) {
            int bb = (recB >> 17) * ACCS2 + 4 * l8;
            atomicAdd(&acc[bb + 0], qpack(pB.x));
            atomicAdd(&acc[bb + 1], qpack(pB.y));
            atomicAdd(&acc[bb + 2], qpack(pB.z));
            atomicAdd(&acc[bb + 3], qpack(pB.w));
            if (l8 == 0) atomicAdd(&cnt[recB >> 17], 1);
        }
    }
    __syncthreads();

    // writeout: wave w handles node-locals [w*16, w*16+16); lane = channel c.
    // channel c lives in 32-bit half (c&1) of u64 slot (c>>1).
    const unsigned int* acc32 = (const unsigned int*)acc;
    float bc = b[lane];
    int half = lane & 1, slot = lane >> 1;
#pragma unroll 4
    for (int r = 0; r < 16; ++r) {
        int nl = wid * 16 + r;
        int node = blk * NPB + nl;
        if (node < N_NODES) {
            unsigned int raw = acc32[(nl * ACCS2 + slot) * 2 + half];
            int qsum = (int)(raw - (unsigned int)cnt[nl] * QBIAS_U);
            float di = dis[node] * INV_QSCALE;
            out[(size_t)node * OUT_CH + lane] = (float)qsum * di + bc;
        }
    }
}

extern "C" void kernel_launch(void* const* d_in, const int* in_sizes, int n_in,
                              void* d_out, int out_size, void* d_ws, size_t ws_size,
                              hipStream_t stream) {
    const float* x  = (const float*)d_in[0];
    const int*   ei = (const int*)d_in[1];
    const float* ew = (const float*)d_in[2];
    const float* W  = (const float*)d_in[3];
    const float* b  = (const float*)d_in[4];
    float* out = (float*)d_out;

    // Workspace layout (4-byte units)
    unsigned int* hs = (unsigned int*)d_ws;                   // N*32 uints (12.8 MB)
    unsigned int* Wb = hs + (size_t)N_NODES * 32;             // 4096 uints
    int*   cursor  = (int*)(Wb + 4096);                       // NBINS*16 (padded)
    float* dis     = (float*)(cursor + NBINS * CURS_STRIDE);  // N
    int2*  brec    = (int2*)(dis + N_NODES);                  // NBINS*bincap int2
    size_t used = (size_t)N_NODES * 32 + 4096 + (size_t)NBINS * CURS_STRIDE
                + (size_t)N_NODES;
    size_t rem  = (ws_size / 4 > used) ? ws_size / 4 - used : 0;
    int bincap  = (int)(rem / (2 * (size_t)NBINS));   // brec = 2 units per slot
    if (bincap > BINCAP_DEF) bincap = BINCAP_DEF;

    wbconv_kernel<<<4, 256, 0, stream>>>(W, Wb, cursor, bincap);
    bin1_kernel<<<NB1, B1T, 0, stream>>>(ei, ew, cursor, brec, bincap);
    bin2_kernel<<<NBINS, 256, 0, stream>>>(cursor, brec, dis, bincap);
    gemm_kernel<<<(N_NODES + 63) / 64, 256, 0, stream>>>(x, Wb, dis, hs);
    bingather_kernel<<<NBINS, 512, 0, stream>>>(cursor, brec, (const uint4*)hs,
                                                dis, b, out, bincap);
}